// Round 3
// baseline (175.530 us; speedup 1.0000x reference)
//
#include <hip/hip_runtime.h>
#include <hip/hip_bf16.h>
#include <cstdint>
#include <cstddef>

// Problem constants (from reference setup_inputs)
#define HH   16
#define BB   4
#define NN   4096
#define DD   1024
#define MM   (BB * NN)      // 16384 rows
#define NC   128            // scan chunks
#define LC   32             // chunk length (NC*LC == NN)
#define EPSV 1e-6f

typedef short short8 __attribute__((ext_vector_type(8)));   // 8 x bf16 (4 VGPRs)
typedef float floatx4 __attribute__((ext_vector_type(4)));

__device__ __forceinline__ void async_copy16(const void* g, void* l) {
    __builtin_amdgcn_global_load_lds(
        (const __attribute__((address_space(1))) void*)g,
        (__attribute__((address_space(3))) void*)l, 16, 0, 0);
}

__device__ __forceinline__ uint2 pack_bf16x4(float a, float b, float c, float d) {
    union { __hip_bfloat16 h[4]; uint2 u; } cv;
    cv.h[0] = __float2bfloat16(a); cv.h[1] = __float2bfloat16(b);
    cv.h[2] = __float2bfloat16(c); cv.h[3] = __float2bfloat16(d);
    return cv.u;
}

__device__ __forceinline__ float sigmoidf(float a) {
    return 1.f / (1.f + expf(-a));
}

// ---- W'[i,j] = o_w[i,j] * nw[j]  (bf16), float4 vectorized ---------------
__global__ void k_wconv(const float* __restrict__ ow, const float* __restrict__ nw,
                        __hip_bfloat16* __restrict__ wp) {
    size_t i4 = (size_t)blockIdx.x * 256 + threadIdx.x;  // over D*D/4
    int j = (int)((i4 * 4) & (DD - 1));
    float4 v = ((const float4*)ow)[i4];
    ((uint2*)wp)[i4] = pack_bf16x4(v.x * nw[j], v.y * nw[j + 1],
                                   v.z * nw[j + 2], v.w * nw[j + 3]);
}

// ---- pass A: chunk-local scan end values (float4 per thread) --------------
__global__ void k_chunk_end(const float* __restrict__ x, const float* __restrict__ ld,
                            float* __restrict__ E) {
    int b = blockIdx.x >> 7, c = blockIdx.x & (NC - 1);
    int j4 = threadIdx.x;                // float4 channel group 0..255
    float lam = sigmoidf(ld[j4 >> 4]);   // 4-ch group never crosses a head
    const float4* xp = (const float4*)(x + ((size_t)(b * NN + c * LC)) * DD) + j4;
    float4 e = {0.f, 0.f, 0.f, 0.f};
    #pragma unroll
    for (int t = 0; t < LC; ++t) {
        float4 v = xp[(size_t)t * (DD / 4)];
        e.x = fmaf(lam, e.x, v.x); e.y = fmaf(lam, e.y, v.y);
        e.z = fmaf(lam, e.z, v.z); e.w = fmaf(lam, e.w, v.w);
    }
    ((float4*)(E + (size_t)blockIdx.x * DD))[j4] = e;
}

// ---- pass B: carry prefix via LDS transpose (coalesced global access) -----
__global__ void k_carry(const float* __restrict__ ld, const float* __restrict__ E,
                        float* __restrict__ P) {
    __shared__ float tile[NC][33];       // +1 pad
    int b = blockIdx.x >> 5, jg = blockIdx.x & 31;   // 4 b x 32 j-groups
    int tid = threadIdx.x;               // 256 threads
    int cc = tid >> 5, jj = tid & 31;
    #pragma unroll
    for (int it = 0; it < 16; ++it) {
        int c = it * 8 + cc;
        tile[c][jj] = E[(size_t)(b * NC + c) * DD + jg * 32 + jj];
    }
    __syncthreads();
    if (tid < 32) {
        int j = jg * 32 + tid;           // 32-ch group never crosses a head
        float lam = sigmoidf(ld[j >> 6]);
        float lamL = lam;                // lam^32 via 5 squarings
        lamL *= lamL; lamL *= lamL; lamL *= lamL; lamL *= lamL; lamL *= lamL;
        float p = 0.f;
        for (int c = 0; c < NC; ++c) {
            float e = tile[c][tid];
            tile[c][tid] = p;            // carry INTO chunk c
            p = fmaf(lamL, p, e);
        }
    }
    __syncthreads();
    #pragma unroll
    for (int it = 0; it < 16; ++it) {
        int c = it * 8 + cc;
        P[(size_t)(b * NC + c) * DD + jg * 32 + jj] = tile[c][jj];
    }
}

// ---- pass C: full scan w/ carry, scale, bf16 store, row sum-sq ------------
__global__ void k_scan(const float* __restrict__ x, const float* __restrict__ q,
                       const float* __restrict__ k, const float* __restrict__ ld,
                       const float* __restrict__ P, __hip_bfloat16* __restrict__ obf,
                       float* __restrict__ sumsq) {
    __shared__ float ssq[4][LC];
    int b = blockIdx.x >> 7, c = blockIdx.x & (NC - 1);
    int j4 = threadIdx.x;                // 0..255
    int h = j4 >> 4;                     // head (16 float4-groups per head)
    float lam = sigmoidf(ld[h]);
    float4 q4 = ((const float4*)q)[j4];
    float4 k4 = ((const float4*)k)[j4];
    float ch = q4.x * k4.x + q4.y * k4.y + q4.z * k4.z + q4.w * k4.w;
    #pragma unroll
    for (int off = 1; off < 16; off <<= 1) ch += __shfl_xor(ch, off);  // per-head dot
    int row0 = b * NN + c * LC;
    int lane = threadIdx.x & 63, w = threadIdx.x >> 6;
    const float4* xp = (const float4*)(x + (size_t)row0 * DD) + j4;
    float4 y = ((const float4*)(P + (size_t)blockIdx.x * DD))[j4];
    for (int t = 0; t < LC; ++t) {
        float4 v = xp[(size_t)t * (DD / 4)];
        y.x = fmaf(lam, y.x, v.x); y.y = fmaf(lam, y.y, v.y);
        y.z = fmaf(lam, y.z, v.z); y.w = fmaf(lam, y.w, v.w);
        float ox = ch * y.x, oy = ch * y.y, oz = ch * y.z, ow = ch * y.w;
        ((uint2*)(obf + (size_t)(row0 + t) * DD))[j4] = pack_bf16x4(ox, oy, oz, ow);
        float s = ox * ox + oy * oy + oz * oz + ow * ow;
        #pragma unroll
        for (int off = 32; off > 0; off >>= 1) s += __shfl_xor(s, off);
        if (lane == 0) ssq[w][t] = s;
    }
    __syncthreads();
    if (threadIdx.x < LC) {
        int t = threadIdx.x;
        sumsq[row0 + t] = ssq[0][t] + ssq[1][t] + ssq[2][t] + ssq[3][t];
    }
}

// ---- GEMM: out[m,i] = rs[m] * sum_j A[m,j] * W'[i,j] ----------------------
// 256x256 tile, 512 threads (8 waves, 2x4), K = 32 slabs of K=32, 4-slot LDS
// ring, prefetch 3 slabs ahead. m201-style PHASE SPLIT: each slab consumed as
// two phases of 16 MFMA, each phase = {4-8 ds_read_b128, 2 global_load_lds,
// barrier, lgkmcnt(0), setprio(1), 16 MFMA, setprio(0), barrier}. vmcnt(8)
// only once per slab (trailing barrier) — 2 slabs always stay in flight.
// 2-bit XOR bank swizzle (inverse-swizzled global source, linear LDS dest),
// XCD-grouped bm mapping.
//
// LDS slab layout per [slot][mat]: row-major [256 rows][4 octets][8 bf16];
// LDS octet position p holds global octet (p ^ ((row>>1)&3)).
#define GEMM_STAGE_A(SLOT, S)                                                  \
  do {                                                                         \
    char* _da = (char*)&lds[SLOT][0][0] + w * 1024;                            \
    _Pragma("unroll") for (int _i = 0; _i < 2; ++_i)                           \
      async_copy16(Ag + (size_t)(m0 + _i * 128 + rr) * 1024 + (S) * 32 + oo * 8, \
                   _da + _i * 8192);                                           \
  } while (0)

#define GEMM_STAGE_B(SLOT, S)                                                  \
  do {                                                                         \
    char* _db = (char*)&lds[SLOT][1][0] + w * 1024;                            \
    _Pragma("unroll") for (int _i = 0; _i < 2; ++_i)                           \
      async_copy16(Wg + (size_t)(n0 + _i * 128 + rr) * 1024 + (S) * 32 + oo * 8, \
                   _db + _i * 8192);                                           \
  } while (0)

// Phase A: bf[0..3] + af[0..3] reads, stage A-half of slab S3, 16 MFMA (mt0-3)
#define PHASE_A(SLOT, DO_STAGE, S3)                                            \
  do {                                                                         \
    const short* _a = &lds[SLOT][0][0];                                        \
    const short* _b = &lds[SLOT][1][0];                                        \
    _Pragma("unroll") for (int nt = 0; nt < 4; ++nt)                           \
      bf[nt] = *(const short8*)(_b + (brow_base + nt * 16) * 32 + p_rd * 8);   \
    _Pragma("unroll") for (int mt = 0; mt < 4; ++mt)                           \
      af[mt] = *(const short8*)(_a + (arow_base + mt * 16) * 32 + p_rd * 8);   \
    if (DO_STAGE) GEMM_STAGE_A((S3) & 3, S3);                                  \
    __builtin_amdgcn_s_barrier();                                              \
    asm volatile("s_waitcnt lgkmcnt(0)" ::: "memory");                         \
    __builtin_amdgcn_s_setprio(1);                                             \
    _Pragma("unroll") for (int mt = 0; mt < 4; ++mt) {                         \
      _Pragma("unroll") for (int nt = 0; nt < 4; ++nt)                         \
        acc[mt][nt] = __builtin_amdgcn_mfma_f32_16x16x32_bf16(                 \
            af[mt], bf[nt], acc[mt][nt], 0, 0, 0);                             \
    }                                                                          \
    __builtin_amdgcn_s_setprio(0);                                             \
    __builtin_amdgcn_s_barrier();                                              \
  } while (0)

// Phase B: af[4..7] reads (bf carried over), stage B-half, 16 MFMA (mt4-7).
// Trailing vmcnt+barrier supplied by the caller (slab boundary).
#define PHASE_B(SLOT, DO_STAGE, S3)                                            \
  do {                                                                         \
    const short* _a = &lds[SLOT][0][0];                                        \
    _Pragma("unroll") for (int mt = 0; mt < 4; ++mt)                           \
      af[mt] = *(const short8*)(_a + (arow_base + 64 + mt * 16) * 32 + p_rd * 8); \
    if (DO_STAGE) GEMM_STAGE_B((S3) & 3, S3);                                  \
    __builtin_amdgcn_s_barrier();                                              \
    asm volatile("s_waitcnt lgkmcnt(0)" ::: "memory");                         \
    __builtin_amdgcn_s_setprio(1);                                             \
    _Pragma("unroll") for (int mt = 0; mt < 4; ++mt) {                         \
      _Pragma("unroll") for (int nt = 0; nt < 4; ++nt)                         \
        acc[4 + mt][nt] = __builtin_amdgcn_mfma_f32_16x16x32_bf16(             \
            af[mt], bf[nt], acc[4 + mt][nt], 0, 0, 0);                         \
    }                                                                          \
    __builtin_amdgcn_s_setprio(0);                                             \
  } while (0)

__launch_bounds__(512, 2)
__global__ void k_gemm(const __hip_bfloat16* __restrict__ A,
                       const __hip_bfloat16* __restrict__ W,
                       const float* __restrict__ sumsq, float* __restrict__ out) {
    // [slot][mat(A=0,B=1)][256 rows * 4 octets * 8 shorts] = 128 KiB total
    __shared__ __attribute__((aligned(16))) short lds[4][2][256 * 32];
    const int tid = threadIdx.x;
    const int lane = tid & 63, w = tid >> 6;
    const int wm = w >> 2, wn = w & 3;           // 2x4 wave grid, 128x64 each
    const int g = blockIdx.x;                    // 256 blocks = 1 per CU
    const int xcd = g & 7, idx = g >> 3;
    const int bm = xcd * 8 + (idx >> 2);         // 4 bn-blocks of a bm share an XCD
    const int bn = idx & 3;
    const int m0 = bm * 256, n0 = bn * 256;
    const short* Ag = (const short*)A;
    const short* Wg = (const short*)W;

    // staging geometry: slot s16 = i*512 + tid; row r = s16>>2, octet pos p = s16&3;
    // global octet o = p ^ ((r>>1)&3)  (i*128 rows keeps (r>>1)&3 invariant)
    const int rr = tid >> 2;                     // 0..127
    const int oo = (tid & 3) ^ ((rr >> 1) & 3);

    // read-side swizzled octet (frag row base is a multiple of 16)
    const int p_rd = (lane >> 4) ^ (((lane & 15) >> 1) & 3);
    const int arow_base = wm * 128 + (lane & 15);
    const int brow_base = wn * 64 + (lane & 15);

    floatx4 acc[8][4] = {};
    short8 af[4], bf[4];

    // prologue: stage slabs 0,1,2 (12 loads/thread outstanding), land slab 0
    GEMM_STAGE_A(0, 0); GEMM_STAGE_B(0, 0);
    GEMM_STAGE_A(1, 1); GEMM_STAGE_B(1, 1);
    GEMM_STAGE_A(2, 2); GEMM_STAGE_B(2, 2);
    asm volatile("s_waitcnt vmcnt(8)" ::: "memory");
    __builtin_amdgcn_s_barrier();

    #pragma unroll 1
    for (int s = 0; s < 29; ++s) {
        // slot (s+3)&3 == (s-1)&3: all its reads lgkm-drained in slab s-1,
        // and the boundary barrier below separates them -> restage is safe.
        PHASE_A(s & 3, 1, s + 3);
        PHASE_B(s & 3, 1, s + 3);
        // slab boundary: slab s+1 landed (slabs s+2, s+3 = 8 loads in flight)
        asm volatile("s_waitcnt vmcnt(8)" ::: "memory");
        __builtin_amdgcn_s_barrier();
    }
    // epilogue slabs 29,30,31: drain 8 -> 4 -> 0
    PHASE_A(1, 0, 0); PHASE_B(1, 0, 0);
    asm volatile("s_waitcnt vmcnt(4)" ::: "memory");
    __builtin_amdgcn_s_barrier();
    PHASE_A(2, 0, 0); PHASE_B(2, 0, 0);
    asm volatile("s_waitcnt vmcnt(0)" ::: "memory");
    __builtin_amdgcn_s_barrier();
    PHASE_A(3, 0, 0); PHASE_B(3, 0, 0);

    // epilogue: RMSNorm scale + store. D[m,n]: row = (l>>4)*4+reg, col = l&15
    #pragma unroll
    for (int mt = 0; mt < 8; ++mt) {
        #pragma unroll
        for (int r = 0; r < 4; ++r) {
            int mrow = m0 + wm * 128 + mt * 16 + (lane >> 4) * 4 + r;
            float rs = rsqrtf(sumsq[mrow] * (1.f / 1024.f) + EPSV);
            #pragma unroll
            for (int nt = 0; nt < 4; ++nt) {
                int col = n0 + wn * 64 + nt * 16 + (lane & 15);
                out[(size_t)mrow * 1024 + col] = acc[mt][nt][r] * rs;
            }
        }
    }
}

extern "C" void kernel_launch(void* const* d_in, const int* in_sizes, int n_in,
                              void* d_out, int out_size, void* d_ws, size_t ws_size,
                              hipStream_t stream) {
    const float* x  = (const float*)d_in[0];
    const float* q  = (const float*)d_in[1];
    const float* k  = (const float*)d_in[2];
    const float* ld = (const float*)d_in[3];
    const float* nw = (const float*)d_in[4];
    const float* ow = (const float*)d_in[5];
    float* out = (float*)d_out;

    char* ws = (char*)d_ws;
    // layout (256B aligned): [unused 32f] | sumsq[M]f | E f | P f | W' bf16 | O bf16
    float* sumsq = (float*)(ws + 256);
    float* E     = (float*)(ws + 65792);
    float* P     = (float*)(ws + 2162944);
    __hip_bfloat16* Wp  = (__hip_bfloat16*)(ws + 4260096);
    __hip_bfloat16* Obf = (__hip_bfloat16*)(ws + 6357248);

    k_wconv<<<(DD * DD / 4) / 256, 256, 0, stream>>>(ow, nw, Wp);
    k_chunk_end<<<BB * NC, 256, 0, stream>>>(x, ld, E);
    k_carry<<<BB * 32, 256, 0, stream>>>(ld, E, P);
    k_scan<<<BB * NC, 256, 0, stream>>>(x, q, k, ld, P, Obf, sumsq);
    k_gemm<<<(MM / 256) * (DD / 256), 512, 0, stream>>>(Obf, Wp, sumsq, out);
}

// Round 4
// 175.297 us; speedup vs baseline: 1.0013x; 1.0013x over previous
//
#include <hip/hip_runtime.h>
#include <hip/hip_bf16.h>
#include <cstdint>
#include <cstddef>

// Problem constants (from reference setup_inputs)
#define HH   16
#define BB   4
#define NN   4096
#define DD   1024
#define MM   (BB * NN)      // 16384 rows
#define NC   256            // scan chunks (per batch)
#define LC   16             // chunk length (NC*LC == NN)
#define EPSV 1e-6f

typedef short short8 __attribute__((ext_vector_type(8)));   // 8 x bf16 (4 VGPRs)
typedef float floatx4 __attribute__((ext_vector_type(4)));

__device__ __forceinline__ void async_copy16(const void* g, void* l) {
    __builtin_amdgcn_global_load_lds(
        (const __attribute__((address_space(1))) void*)g,
        (__attribute__((address_space(3))) void*)l, 16, 0, 0);
}

__device__ __forceinline__ uint2 pack_bf16x4(float a, float b, float c, float d) {
    union { __hip_bfloat16 h[4]; uint2 u; } cv;
    cv.h[0] = __float2bfloat16(a); cv.h[1] = __float2bfloat16(b);
    cv.h[2] = __float2bfloat16(c); cv.h[3] = __float2bfloat16(d);
    return cv.u;
}

__device__ __forceinline__ float sigmoidf(float a) {
    return 1.f / (1.f + expf(-a));
}

// ---- fused pass A: chunk-local scan end values + W' conversion ------------
// Blocks [0, BB*NC): chunk-end for chunk (b,c). Blocks [BB*NC, BB*NC+1024):
// W'[i,j] = o_w[i,j]*nw[j] in bf16. Independent work, block-level branch.
__global__ void k_prep(const float* __restrict__ x, const float* __restrict__ ld,
                       float* __restrict__ E, const float* __restrict__ ow,
                       const float* __restrict__ nw, __hip_bfloat16* __restrict__ wp) {
    int g = blockIdx.x;
    if (g < BB * NC) {
        int b = g >> 8, c = g & (NC - 1);
        int j4 = threadIdx.x;                // float4 channel group 0..255
        float lam = sigmoidf(ld[j4 >> 4]);   // 4-ch group never crosses a head
        const float4* xp = (const float4*)(x + ((size_t)(b * NN + c * LC)) * DD) + j4;
        float4 e = {0.f, 0.f, 0.f, 0.f};
        #pragma unroll
        for (int t = 0; t < LC; ++t) {
            float4 v = xp[(size_t)t * (DD / 4)];
            e.x = fmaf(lam, e.x, v.x); e.y = fmaf(lam, e.y, v.y);
            e.z = fmaf(lam, e.z, v.z); e.w = fmaf(lam, e.w, v.w);
        }
        ((float4*)(E + (size_t)g * DD))[j4] = e;
    } else {
        size_t i4 = (size_t)(g - BB * NC) * 256 + threadIdx.x;  // over D*D/4
        int j = (int)((i4 * 4) & (DD - 1));
        float4 v = ((const float4*)ow)[i4];
        ((uint2*)wp)[i4] = pack_bf16x4(v.x * nw[j], v.y * nw[j + 1],
                                       v.z * nw[j + 2], v.w * nw[j + 3]);
    }
}

// ---- pass B: carry prefix via LDS transpose, IN PLACE on E ----------------
// Block (b, jg) owns channels jg*32..+31 of batch b across all NC chunks —
// exclusive slice, so reading E and writing carries back is race-free.
__global__ void k_carry(const float* __restrict__ ld, float* __restrict__ E) {
    __shared__ float tile[NC][33];       // 256 x 33 x 4B = 33.8 KB (+1 pad)
    int b = blockIdx.x >> 5, jg = blockIdx.x & 31;   // 4 b x 32 j-groups
    int tid = threadIdx.x;               // 256 threads
    int cc = tid >> 5, jj = tid & 31;
    #pragma unroll
    for (int it = 0; it < NC / 8; ++it) {
        int c = it * 8 + cc;
        tile[c][jj] = E[(size_t)(b * NC + c) * DD + jg * 32 + jj];
    }
    __syncthreads();
    if (tid < 32) {
        int j = jg * 32 + tid;           // 32-ch group never crosses a head
        float lam = sigmoidf(ld[j >> 6]);
        float lamL = lam;                // lam^16 via 4 squarings
        lamL *= lamL; lamL *= lamL; lamL *= lamL; lamL *= lamL;
        float p = 0.f;
        for (int c = 0; c < NC; ++c) {
            float e = tile[c][tid];
            tile[c][tid] = p;            // carry INTO chunk c
            p = fmaf(lamL, p, e);
        }
    }
    __syncthreads();
    #pragma unroll
    for (int it = 0; it < NC / 8; ++it) {
        int c = it * 8 + cc;
        E[(size_t)(b * NC + c) * DD + jg * 32 + jj] = tile[c][jj];
    }
}

// ---- pass C: full scan w/ carry, scale, bf16 store, row sum-sq ------------
// 1024 blocks (4/CU, 16 waves/CU) for latency hiding. Block owns its rows.
__global__ void k_scan(const float* __restrict__ x, const float* __restrict__ q,
                       const float* __restrict__ k, const float* __restrict__ ld,
                       const float* __restrict__ P, __hip_bfloat16* __restrict__ obf,
                       float* __restrict__ sumsq) {
    __shared__ float ssq[4][LC];
    int b = blockIdx.x >> 8, c = blockIdx.x & (NC - 1);
    int j4 = threadIdx.x;                // 0..255
    int h = j4 >> 4;                     // head (16 float4-groups per head)
    float lam = sigmoidf(ld[h]);
    float4 q4 = ((const float4*)q)[j4];
    float4 k4 = ((const float4*)k)[j4];
    float ch = q4.x * k4.x + q4.y * k4.y + q4.z * k4.z + q4.w * k4.w;
    #pragma unroll
    for (int off = 1; off < 16; off <<= 1) ch += __shfl_xor(ch, off);  // per-head dot
    int row0 = b * NN + c * LC;
    int lane = threadIdx.x & 63, w = threadIdx.x >> 6;
    const float4* xp = (const float4*)(x + (size_t)row0 * DD) + j4;
    float4 y = ((const float4*)(P + (size_t)blockIdx.x * DD))[j4];
    #pragma unroll
    for (int t = 0; t < LC; ++t) {
        float4 v = xp[(size_t)t * (DD / 4)];
        y.x = fmaf(lam, y.x, v.x); y.y = fmaf(lam, y.y, v.y);
        y.z = fmaf(lam, y.z, v.z); y.w = fmaf(lam, y.w, v.w);
        float ox = ch * y.x, oy = ch * y.y, oz = ch * y.z, ow = ch * y.w;
        ((uint2*)(obf + (size_t)(row0 + t) * DD))[j4] = pack_bf16x4(ox, oy, oz, ow);
        float s = ox * ox + oy * oy + oz * oz + ow * ow;
        #pragma unroll
        for (int off = 32; off > 0; off >>= 1) s += __shfl_xor(s, off);
        if (lane == 0) ssq[w][t] = s;
    }
    __syncthreads();
    if (threadIdx.x < LC) {
        int t = threadIdx.x;
        sumsq[row0 + t] = ssq[0][t] + ssq[1][t] + ssq[2][t] + ssq[3][t];
    }
}

// ---- GEMM: out[m,i] = rs[m] * sum_j A[m,j] * W'[i,j] ----------------------
// (unchanged from previous round for attribution)
// 256x256 tile, 512 threads (8 waves, 2x4), K = 32 slabs of K=32, 4-slot LDS
// ring, prefetch 3 slabs ahead, phase-split consume, counted vmcnt, XOR bank
// swizzle, XCD-grouped bm mapping.
#define GEMM_STAGE_A(SLOT, S)                                                  \
  do {                                                                         \
    char* _da = (char*)&lds[SLOT][0][0] + w * 1024;                            \
    _Pragma("unroll") for (int _i = 0; _i < 2; ++_i)                           \
      async_copy16(Ag + (size_t)(m0 + _i * 128 + rr) * 1024 + (S) * 32 + oo * 8, \
                   _da + _i * 8192);                                           \
  } while (0)

#define GEMM_STAGE_B(SLOT, S)                                                  \
  do {                                                                         \
    char* _db = (char*)&lds[SLOT][1][0] + w * 1024;                            \
    _Pragma("unroll") for (int _i = 0; _i < 2; ++_i)                           \
      async_copy16(Wg + (size_t)(n0 + _i * 128 + rr) * 1024 + (S) * 32 + oo * 8, \
                   _db + _i * 8192);                                           \
  } while (0)

#define PHASE_A(SLOT, DO_STAGE, S3)                                            \
  do {                                                                         \
    const short* _a = &lds[SLOT][0][0];                                        \
    const short* _b = &lds[SLOT][1][0];                                        \
    _Pragma("unroll") for (int nt = 0; nt < 4; ++nt)                           \
      bf[nt] = *(const short8*)(_b + (brow_base + nt * 16) * 32 + p_rd * 8);   \
    _Pragma("unroll") for (int mt = 0; mt < 4; ++mt)                           \
      af[mt] = *(const short8*)(_a + (arow_base + mt * 16) * 32 + p_rd * 8);   \
    if (DO_STAGE) GEMM_STAGE_A((S3) & 3, S3);                                  \
    __builtin_amdgcn_s_barrier();                                              \
    asm volatile("s_waitcnt lgkmcnt(0)" ::: "memory");                         \
    __builtin_amdgcn_s_setprio(1);                                             \
    _Pragma("unroll") for (int mt = 0; mt < 4; ++mt) {                         \
      _Pragma("unroll") for (int nt = 0; nt < 4; ++nt)                         \
        acc[mt][nt] = __builtin_amdgcn_mfma_f32_16x16x32_bf16(                 \
            af[mt], bf[nt], acc[mt][nt], 0, 0, 0);                             \
    }                                                                          \
    __builtin_amdgcn_s_setprio(0);                                             \
    __builtin_amdgcn_s_barrier();                                              \
  } while (0)

#define PHASE_B(SLOT, DO_STAGE, S3)                                            \
  do {                                                                         \
    const short* _a = &lds[SLOT][0][0];                                        \
    _Pragma("unroll") for (int mt = 0; mt < 4; ++mt)                           \
      af[mt] = *(const short8*)(_a + (arow_base + 64 + mt * 16) * 32 + p_rd * 8); \
    if (DO_STAGE) GEMM_STAGE_B((S3) & 3, S3);                                  \
    __builtin_amdgcn_s_barrier();                                              \
    asm volatile("s_waitcnt lgkmcnt(0)" ::: "memory");                         \
    __builtin_amdgcn_s_setprio(1);                                             \
    _Pragma("unroll") for (int mt = 0; mt < 4; ++mt) {                         \
      _Pragma("unroll") for (int nt = 0; nt < 4; ++nt)                         \
        acc[4 + mt][nt] = __builtin_amdgcn_mfma_f32_16x16x32_bf16(             \
            af[mt], bf[nt], acc[4 + mt][nt], 0, 0, 0);                         \
    }                                                                          \
    __builtin_amdgcn_s_setprio(0);                                             \
  } while (0)

__launch_bounds__(512, 2)
__global__ void k_gemm(const __hip_bfloat16* __restrict__ A,
                       const __hip_bfloat16* __restrict__ W,
                       const float* __restrict__ sumsq, float* __restrict__ out) {
    __shared__ __attribute__((aligned(16))) short lds[4][2][256 * 32];
    const int tid = threadIdx.x;
    const int lane = tid & 63, w = tid >> 6;
    const int wm = w >> 2, wn = w & 3;           // 2x4 wave grid, 128x64 each
    const int g = blockIdx.x;                    // 256 blocks = 1 per CU
    const int xcd = g & 7, idx = g >> 3;
    const int bm = xcd * 8 + (idx >> 2);         // 4 bn-blocks of a bm share an XCD
    const int bn = idx & 3;
    const int m0 = bm * 256, n0 = bn * 256;
    const short* Ag = (const short*)A;
    const short* Wg = (const short*)W;

    const int rr = tid >> 2;                     // 0..127
    const int oo = (tid & 3) ^ ((rr >> 1) & 3);

    const int p_rd = (lane >> 4) ^ (((lane & 15) >> 1) & 3);
    const int arow_base = wm * 128 + (lane & 15);
    const int brow_base = wn * 64 + (lane & 15);

    floatx4 acc[8][4] = {};
    short8 af[4], bf[4];

    GEMM_STAGE_A(0, 0); GEMM_STAGE_B(0, 0);
    GEMM_STAGE_A(1, 1); GEMM_STAGE_B(1, 1);
    GEMM_STAGE_A(2, 2); GEMM_STAGE_B(2, 2);
    asm volatile("s_waitcnt vmcnt(8)" ::: "memory");
    __builtin_amdgcn_s_barrier();

    #pragma unroll 1
    for (int s = 0; s < 29; ++s) {
        PHASE_A(s & 3, 1, s + 3);
        PHASE_B(s & 3, 1, s + 3);
        asm volatile("s_waitcnt vmcnt(8)" ::: "memory");
        __builtin_amdgcn_s_barrier();
    }
    PHASE_A(1, 0, 0); PHASE_B(1, 0, 0);
    asm volatile("s_waitcnt vmcnt(4)" ::: "memory");
    __builtin_amdgcn_s_barrier();
    PHASE_A(2, 0, 0); PHASE_B(2, 0, 0);
    asm volatile("s_waitcnt vmcnt(0)" ::: "memory");
    __builtin_amdgcn_s_barrier();
    PHASE_A(3, 0, 0); PHASE_B(3, 0, 0);

    #pragma unroll
    for (int mt = 0; mt < 8; ++mt) {
        #pragma unroll
        for (int r = 0; r < 4; ++r) {
            int mrow = m0 + wm * 128 + mt * 16 + (lane >> 4) * 4 + r;
            float rs = rsqrtf(sumsq[mrow] * (1.f / 1024.f) + EPSV);
            #pragma unroll
            for (int nt = 0; nt < 4; ++nt) {
                int col = n0 + wn * 64 + nt * 16 + (lane & 15);
                out[(size_t)mrow * 1024 + col] = acc[mt][nt][r] * rs;
            }
        }
    }
}

extern "C" void kernel_launch(void* const* d_in, const int* in_sizes, int n_in,
                              void* d_out, int out_size, void* d_ws, size_t ws_size,
                              hipStream_t stream) {
    const float* x  = (const float*)d_in[0];
    const float* q  = (const float*)d_in[1];
    const float* k  = (const float*)d_in[2];
    const float* ld = (const float*)d_in[3];
    const float* nw = (const float*)d_in[4];
    const float* ow = (const float*)d_in[5];
    float* out = (float*)d_out;

    char* ws = (char*)d_ws;
    // layout (256B aligned): [unused 32f] | sumsq[M]f | E f (carry in place) |
    //                        W' bf16 | O bf16   — total ~38 MB
    float* sumsq = (float*)(ws + 256);
    float* E     = (float*)(ws + 65792);           // 4 MB (BB*NC*DD*4)
    __hip_bfloat16* Wp  = (__hip_bfloat16*)(ws + 4260096);   // 2 MB
    __hip_bfloat16* Obf = (__hip_bfloat16*)(ws + 6357248);   // 32 MB

    // fused chunk-end (1024 blocks) + wconv (1024 blocks)
    k_prep<<<BB * NC + (DD * DD / 4) / 256, 256, 0, stream>>>(x, ld, E, ow, nw, Wp);
    k_carry<<<BB * 32, 256, 0, stream>>>(ld, E);
    k_scan<<<BB * NC, 256, 0, stream>>>(x, q, k, ld, E, Obf, sumsq);
    k_gemm<<<(MM / 256) * (DD / 256), 512, 0, stream>>>(Obf, Wp, sumsq, out);
}